// Round 16
// baseline (22.498 us; speedup 1.0000x reference)
//
#include <hip/hip_runtime.h>

// Chamfer loss via MFMA, B=16, N=4096, D=3, fp32 in/out. Single dispatch.
// d2[p][q] = ||p||^2 + ||q||^2 - 2 p.q as one 32x32x16 f16 MFMA per tile,
// hi/lo f16 split (error ~1e-3; ||q||^2 added per-column after the min).
// 1024-thread blocks (16 waves = 4 waves/SIMD), 1 block/CU, 256 blocks.
// ALL 4096 rows staged ONCE into 128 KB LDS -> exactly ONE barrier; the
// 128-tile compute loop is barrier-free (no chunk convoys). Inner loop:
// 2-slot software-pipelined accumulator (tree(t) runs two MFMA issues after
// its MFMA) + 4-deep named-register A prefetch. Max 3 live floatx16, all
// indices static, unconditional main loop + peeled epilogue (r11/r12
// lesson: conditional/dynamic register state -> scratch spill).

typedef _Float16 half8    __attribute__((ext_vector_type(8)));
typedef float    floatx16 __attribute__((ext_vector_type(16)));

#define CH_B 16
#define CH_N 4096
#define CH_BLOCK 1024                  // 16 waves
#define CH_COLS 512                    // output cols per block (32/wave)
#define CH_NCT (CH_N / CH_COLS)        // 8 col-tiles per (dir,b)
#define CH_CT (CH_N / 32)              // 128 row-tiles (all rows resident)
#define CH_NBLK (2 * CH_B * CH_NCT)    // 256 blocks (1 per CU)

__global__ __launch_bounds__(CH_BLOCK, 4) void chamfer_one(
    const float* __restrict__ src, const float* __restrict__ trg,
    float* __restrict__ out_all)
{
    __shared__ half8 sp[CH_CT * 64];   // 128 KB: all A-fragments

    const int tid  = threadIdx.x;
    const int lane = tid & 63;
    const int wave = tid >> 6;            // 0..15
    const int l31  = lane & 31;
    const int lhi  = lane >> 5;

    const int L   = blockIdx.x;           // 0..255
    const int ct  = L & (CH_NCT - 1);     // col-tile
    const int bz  = L >> 3;               // dir*16 + b
    const int b   = bz & (CH_B - 1);
    const int dir = bz >> 4;

    const float* P  = dir ? trg : src;
    const float* Q  = dir ? src : trg;
    const float* Pb = P + (size_t)b * CH_N * 3;
    const float* Qb = Q + (size_t)b * CH_N * 3;
    float* out = out_all + ((size_t)dir * CH_B + b) * CH_N;

    // ---- B fragment: 32 cols per wave ----
    const int col0 = ct * CH_COLS + wave * 32 + l31;
    float qn, m = __builtin_inff();
    half8 bfrag;
    {
        const float qx = Qb[col0 * 3 + 0], qy = Qb[col0 * 3 + 1], qz = Qb[col0 * 3 + 2];
        qn = qx * qx + qy * qy + qz * qz;
        const _Float16 xh = (_Float16)qx, yh = (_Float16)qy, zh = (_Float16)qz;
        const _Float16 xl = (_Float16)(qx - (float)xh);
        const _Float16 yl = (_Float16)(qy - (float)yh);
        const _Float16 zl = (_Float16)(qz - (float)zh);
        half8 f;
        if (lhi == 0) {      // k = 0..7
            f[0] = (_Float16)1.0f; f[1] = (_Float16)1.0f;
            f[2] = xh; f[3] = yh; f[4] = zh;
            f[5] = xh; f[6] = yh; f[7] = zh;
        } else {             // k = 8..15
            f[0] = xl; f[1] = yl; f[2] = zl;
            f[3] = (_Float16)0.0f; f[4] = (_Float16)0.0f;
            f[5] = (_Float16)0.0f; f[6] = (_Float16)0.0f; f[7] = (_Float16)0.0f;
        }
        bfrag = f;
    }

    // ---- stage ALL rows: 4 points/thread from 3 coalesced float4 loads ----
    // (r7-verified unpack; Pb is 16B-aligned: b*4096*3*4 is a multiple of 16.)
    {
        const float4* p4 = (const float4*)Pb;
        const float4 v0 = p4[tid * 3 + 0];
        const float4 v1 = p4[tid * 3 + 1];
        const float4 v2 = p4[tid * 3 + 2];
        const float px[4] = {v0.x, v0.w, v1.z, v2.y};
        const float py[4] = {v0.y, v1.x, v1.w, v2.z};
        const float pz[4] = {v0.z, v1.y, v2.x, v2.w};
        #pragma unroll
        for (int j = 0; j < 4; ++j) {
            const float ax = -2.0f * px[j], ay = -2.0f * py[j], az = -2.0f * pz[j];
            const float pn = px[j] * px[j] + py[j] * py[j] + pz[j] * pz[j];
            const _Float16 axh = (_Float16)ax, ayh = (_Float16)ay, azh = (_Float16)az;
            const _Float16 axl = (_Float16)(ax - (float)axh);
            const _Float16 ayl = (_Float16)(ay - (float)ayh);
            const _Float16 azl = (_Float16)(az - (float)azh);
            const _Float16 pnh = (_Float16)pn, pnl = (_Float16)(pn - (float)pnh);
            const _Float16 z0 = (_Float16)0.0f;
            const half8 k0 = {pnh, pnl, axh, ayh, azh, axl, ayl, azl};  // k 0..7
            const half8 k1 = {axh, ayh, azh, z0, z0, z0, z0, z0};       // k 8..15
            const int r = tid * 4 + j;
            sp[(r >> 5) * 64 + (r & 31)]      = k0;
            sp[(r >> 5) * 64 + 32 + (r & 31)] = k1;
        }
    }
    __syncthreads();   // the ONLY barrier

    const floatx16 zero = {0.f,0.f,0.f,0.f,0.f,0.f,0.f,0.f,
                           0.f,0.f,0.f,0.f,0.f,0.f,0.f,0.f};

    // min3-shaped reduction of one MFMA result into m
    auto tree = [&](const floatx16& d) {
        const float u0 = fminf(fminf(d[0],  d[1]),  d[2]);
        const float u1 = fminf(fminf(d[3],  d[4]),  d[5]);
        const float u2 = fminf(fminf(d[6],  d[7]),  d[8]);
        const float u3 = fminf(fminf(d[9],  d[10]), d[11]);
        const float u4 = fminf(fminf(d[12], d[13]), d[14]);
        const float v  = fminf(fminf(u0, u1), u2);
        const float w  = fminf(fminf(u3, u4), d[15]);
        m = fminf(fminf(m, v), w);
    };

    // ---- barrier-free compute: 128 tiles, 2-slot d pipeline, 4-deep A ----
    half8 A0 = sp[0 * 64 + lane];
    half8 A1 = sp[1 * 64 + lane];
    half8 A2 = sp[2 * 64 + lane];
    half8 A3 = sp[3 * 64 + lane];
    floatx16 d0 = __builtin_amdgcn_mfma_f32_32x32x16_f16(A0, bfrag, zero, 0, 0, 0);
    floatx16 d1 = __builtin_amdgcn_mfma_f32_32x32x16_f16(A1, bfrag, zero, 0, 0, 0);

    #pragma unroll 1
    for (int t = 0; t <= CH_CT - 8; t += 4) {   // t = 0..120; trees tiles 0..123
        floatx16 d2 = __builtin_amdgcn_mfma_f32_32x32x16_f16(A2, bfrag, zero, 0, 0, 0);
        A0 = sp[(t + 4) * 64 + lane];
        tree(d0);
        floatx16 d3 = __builtin_amdgcn_mfma_f32_32x32x16_f16(A3, bfrag, zero, 0, 0, 0);
        A1 = sp[(t + 5) * 64 + lane];
        tree(d1);
        d0 = __builtin_amdgcn_mfma_f32_32x32x16_f16(A0, bfrag, zero, 0, 0, 0);
        A2 = sp[(t + 6) * 64 + lane];
        tree(d2);
        d1 = __builtin_amdgcn_mfma_f32_32x32x16_f16(A1, bfrag, zero, 0, 0, 0);
        A3 = sp[(t + 7) * 64 + lane];
        tree(d3);
    }
    // epilogue: d0=tile124, d1=tile125, A2=tile126, A3=tile127
    {
        floatx16 e2 = __builtin_amdgcn_mfma_f32_32x32x16_f16(A2, bfrag, zero, 0, 0, 0);
        tree(d0);
        floatx16 e3 = __builtin_amdgcn_mfma_f32_32x32x16_f16(A3, bfrag, zero, 0, 0, 0);
        tree(d1);
        tree(e2);
        tree(e3);
    }

    // ---- epilogue: add ||q||^2, clamp >=0, fold row-halves, plain store ----
    float v = fmaxf(m + qn, 0.0f);
    v = fminf(v, __shfl_xor(v, 32));
    if (lane < 32) out[col0] = v;
}

extern "C" void kernel_launch(void* const* d_in, const int* in_sizes, int n_in,
                              void* d_out, int out_size, void* d_ws, size_t ws_size,
                              hipStream_t stream) {
    const float* src = (const float*)d_in[0];
    const float* trg = (const float*)d_in[1];
    float* out = (float*)d_out;

    chamfer_one<<<dim3(CH_NBLK), dim3(CH_BLOCK), 0, stream>>>(src, trg, out);
}

// Round 17
// 18.300 us; speedup vs baseline: 1.2294x; 1.2294x over previous
//
#include <hip/hip_runtime.h>

// Chamfer loss via MFMA, B=16, N=4096, D=3, fp32 in/out. Single dispatch.
// d2[p][q] = ||p||^2 + ||q||^2 - 2 p.q, now as one 32x32x8 f16 MFMA per tile
// (legacy 2-reg shape; our encoding needs only 8 K-slots).
//   k0-3 (lanes 0-31):  A = {pn_h, ax_h, ay_h, az_h},  B = {1, qx_h, qy_h, qz_h}
//   k4-7 (lanes 32-63): A = {pn_l, ax_l, ay_l, az_l},  B = {1, qx_h, qy_h, qz_h}
// (a = -2p; A-side hi/lo corrected, B hi-only: residual error a.q_l ~5e-3,
//  threshold is 0.12 -> ample margin. ||q||^2 added per-column after min.)
// Structure identical to r15 (best, 21.4us): 1024-thread blocks (16 waves =
// 4 waves/SIMD), 1 block/CU, 512 cols/block, 4 double-buffered 1024-row LDS
// chunks, 1-slot software-pipelined accumulator + 4-deep named A prefetch.

typedef _Float16 half4    __attribute__((ext_vector_type(4)));
typedef float    floatx16 __attribute__((ext_vector_type(16)));

#define CH_B 16
#define CH_N 4096
#define CH_BLOCK 1024                  // 16 waves
#define CH_COLS 512                    // output cols per block (32/wave)
#define CH_NCT (CH_N / CH_COLS)        // 8 col-tiles per (dir,b)
#define CH_CHUNK 1024                  // staged rows per chunk
#define CH_NCHUNK (CH_N / CH_CHUNK)    // 4
#define CH_CT (CH_CHUNK / 32)          // 32 row-tiles per chunk
#define CH_NBLK (2 * CH_B * CH_NCT)    // 256 blocks (1 per CU)

__global__ __launch_bounds__(CH_BLOCK, 4) void chamfer_one(
    const float* __restrict__ src, const float* __restrict__ trg,
    float* __restrict__ out_all)
{
    __shared__ half4 sp[2][CH_CT * 64];   // 2 x 16 KB A-fragment buffers

    const int tid  = threadIdx.x;
    const int lane = tid & 63;
    const int wave = tid >> 6;            // 0..15
    const int l31  = lane & 31;

    const int L   = blockIdx.x;           // 0..255
    const int ct  = L & (CH_NCT - 1);     // col-tile
    const int bz  = L >> 3;               // dir*16 + b
    const int b   = bz & (CH_B - 1);
    const int dir = bz >> 4;

    const float* P  = dir ? trg : src;
    const float* Q  = dir ? src : trg;
    const float* Pb = P + (size_t)b * CH_N * 3;
    const float* Qb = Q + (size_t)b * CH_N * 3;
    float* out = out_all + ((size_t)dir * CH_B + b) * CH_N;

    // ---- B fragment: 32 cols per wave, lane-uniform hi-only encoding ----
    const int col0 = ct * CH_COLS + wave * 32 + l31;
    float qn, m = __builtin_inff();
    half4 bfrag;
    {
        const float qx = Qb[col0 * 3 + 0], qy = Qb[col0 * 3 + 1], qz = Qb[col0 * 3 + 2];
        qn = qx * qx + qy * qy + qz * qz;
        bfrag[0] = (_Float16)1.0f;
        bfrag[1] = (_Float16)qx;
        bfrag[2] = (_Float16)qy;
        bfrag[3] = (_Float16)qz;
    }

    // ---- staging: 1 row per thread per chunk (scalar loads) ----
    float pa[3];
    auto loadpts = [&](int c) {
        const float* base = Pb + ((size_t)c * CH_CHUNK + tid) * 3;
        pa[0] = base[0];
        pa[1] = base[1];
        pa[2] = base[2];
    };
    auto writept = [&](int buf) {
        const float ax = -2.0f * pa[0], ay = -2.0f * pa[1], az = -2.0f * pa[2];
        const float pn = pa[0] * pa[0] + pa[1] * pa[1] + pa[2] * pa[2];
        const _Float16 axh = (_Float16)ax, ayh = (_Float16)ay, azh = (_Float16)az;
        const _Float16 pnh = (_Float16)pn;
        const half4 k0 = {pnh, axh, ayh, azh};                       // k 0..3
        const half4 k1 = {(_Float16)(pn - (float)pnh),
                          (_Float16)(ax - (float)axh),
                          (_Float16)(ay - (float)ayh),
                          (_Float16)(az - (float)azh)};              // k 4..7
        sp[buf][(tid >> 5) * 64 + (tid & 31)]      = k0;
        sp[buf][(tid >> 5) * 64 + 32 + (tid & 31)] = k1;
    };

    // prologue: stage chunk 0
    loadpts(0);
    writept(0);
    __syncthreads();

    const floatx16 zero = {0.f,0.f,0.f,0.f,0.f,0.f,0.f,0.f,
                           0.f,0.f,0.f,0.f,0.f,0.f,0.f,0.f};

    // min3-shaped reduction of one MFMA result into m
    auto tree = [&](const floatx16& d) {
        const float u0 = fminf(fminf(d[0],  d[1]),  d[2]);
        const float u1 = fminf(fminf(d[3],  d[4]),  d[5]);
        const float u2 = fminf(fminf(d[6],  d[7]),  d[8]);
        const float u3 = fminf(fminf(d[9],  d[10]), d[11]);
        const float u4 = fminf(fminf(d[12], d[13]), d[14]);
        const float v  = fminf(fminf(u0, u1), u2);
        const float w  = fminf(fminf(u3, u4), d[15]);
        m = fminf(fminf(m, v), w);
    };

    #pragma unroll 1
    for (int c = 0; c < CH_NCHUNK; ++c) {
        const int cur = c & 1;
        const bool more = (c + 1 < CH_NCHUNK);
        if (more) loadpts(c + 1);   // issue early; consumed after compute

        const half4* buf = sp[cur];

        // 4-deep A prefetch + 1-slot d pipeline (max 2 live floatx16)
        half4 A0 = buf[0 * 64 + lane];
        half4 A1 = buf[1 * 64 + lane];
        half4 A2 = buf[2 * 64 + lane];
        half4 A3 = buf[3 * 64 + lane];
        floatx16 d0 = __builtin_amdgcn_mfma_f32_32x32x8f16(A0, bfrag, zero, 0, 0, 0);

        #pragma unroll 1
        for (int t = 0; t <= CH_CT - 8; t += 4) {   // t = 0..24, tiles 0..27
            floatx16 d1 = __builtin_amdgcn_mfma_f32_32x32x8f16(A1, bfrag, zero, 0, 0, 0);
            A0 = buf[(t + 4) * 64 + lane];
            tree(d0);
            floatx16 d2 = __builtin_amdgcn_mfma_f32_32x32x8f16(A2, bfrag, zero, 0, 0, 0);
            A1 = buf[(t + 5) * 64 + lane];
            tree(d1);
            floatx16 d3 = __builtin_amdgcn_mfma_f32_32x32x8f16(A3, bfrag, zero, 0, 0, 0);
            A2 = buf[(t + 6) * 64 + lane];
            tree(d2);
            d0 = __builtin_amdgcn_mfma_f32_32x32x8f16(A0, bfrag, zero, 0, 0, 0);
            A3 = buf[(t + 7) * 64 + lane];
            tree(d3);
        }
        // epilogue: tiles CT-4..CT-1 (d0 already holds tile CT-4's result)
        {
            floatx16 e1 = __builtin_amdgcn_mfma_f32_32x32x8f16(A1, bfrag, zero, 0, 0, 0);
            tree(d0);
            floatx16 e2 = __builtin_amdgcn_mfma_f32_32x32x8f16(A2, bfrag, zero, 0, 0, 0);
            tree(e1);
            floatx16 e3 = __builtin_amdgcn_mfma_f32_32x32x8f16(A3, bfrag, zero, 0, 0, 0);
            tree(e2);
            tree(e3);
        }

        if (more) writept(cur ^ 1);   // LDS writes late (load latency hidden)
        __syncthreads();
    }

    // ---- epilogue: add ||q||^2, clamp >=0, fold row-halves, plain store ----
    float v = fmaxf(m + qn, 0.0f);
    v = fminf(v, __shfl_xor(v, 32));
    if (lane < 32) out[col0] = v;
}

extern "C" void kernel_launch(void* const* d_in, const int* in_sizes, int n_in,
                              void* d_out, int out_size, void* d_ws, size_t ws_size,
                              hipStream_t stream) {
    const float* src = (const float*)d_in[0];
    const float* trg = (const float*)d_in[1];
    float* out = (float*)d_out;

    chamfer_one<<<dim3(CH_NBLK), dim3(CH_BLOCK), 0, stream>>>(src, trg, out);
}

// Round 18
// 18.202 us; speedup vs baseline: 1.2360x; 1.0054x over previous
//
#include <hip/hip_runtime.h>

// Chamfer loss via MFMA, B=16, N=4096, D=3, fp32 in/out. Single dispatch.
// d2[p][q] = ||p||^2 + ||q||^2 - 2 p.q as one 32x32x8 f16 MFMA per tile
// (legacy 2-reg shape; encoding needs only 8 K-slots).
//   k0-3 (lanes 0-31):  A = {pn_h, ax_h, ay_h, az_h},  B = {1, qx_h, qy_h, qz_h}
//   k4-7 (lanes 32-63): A = {pn_l, ax_l, ay_l, az_l},  B = {1, qx_h, qy_h, qz_h}
// (a = -2p; A-side hi/lo corrected, B hi-only: absmax 0.016 << 0.12 thr.)
// Structure = r17 (18.3us) with ONE change: 2-slot software-pipelined
// accumulator -- tree(t) runs TWO MFMA issues after its own MFMA, so MFMA
// result latency is fully off the critical path. Max 3 live floatx16 +
// 4-deep named A prefetch; all indices static (r11/r12 spill lesson).

typedef _Float16 half4    __attribute__((ext_vector_type(4)));
typedef float    floatx16 __attribute__((ext_vector_type(16)));

#define CH_B 16
#define CH_N 4096
#define CH_BLOCK 1024                  // 16 waves
#define CH_COLS 512                    // output cols per block (32/wave)
#define CH_NCT (CH_N / CH_COLS)        // 8 col-tiles per (dir,b)
#define CH_CHUNK 1024                  // staged rows per chunk
#define CH_NCHUNK (CH_N / CH_CHUNK)    // 4
#define CH_CT (CH_CHUNK / 32)          // 32 row-tiles per chunk
#define CH_NBLK (2 * CH_B * CH_NCT)    // 256 blocks (1 per CU)

__global__ __launch_bounds__(CH_BLOCK, 4) void chamfer_one(
    const float* __restrict__ src, const float* __restrict__ trg,
    float* __restrict__ out_all)
{
    __shared__ half4 sp[2][CH_CT * 64];   // 2 x 16 KB A-fragment buffers

    const int tid  = threadIdx.x;
    const int lane = tid & 63;
    const int wave = tid >> 6;            // 0..15
    const int l31  = lane & 31;

    const int L   = blockIdx.x;           // 0..255
    const int ct  = L & (CH_NCT - 1);     // col-tile
    const int bz  = L >> 3;               // dir*16 + b
    const int b   = bz & (CH_B - 1);
    const int dir = bz >> 4;

    const float* P  = dir ? trg : src;
    const float* Q  = dir ? src : trg;
    const float* Pb = P + (size_t)b * CH_N * 3;
    const float* Qb = Q + (size_t)b * CH_N * 3;
    float* out = out_all + ((size_t)dir * CH_B + b) * CH_N;

    // ---- B fragment: 32 cols per wave, lane-uniform hi-only encoding ----
    const int col0 = ct * CH_COLS + wave * 32 + l31;
    float qn, m = __builtin_inff();
    half4 bfrag;
    {
        const float qx = Qb[col0 * 3 + 0], qy = Qb[col0 * 3 + 1], qz = Qb[col0 * 3 + 2];
        qn = qx * qx + qy * qy + qz * qz;
        bfrag[0] = (_Float16)1.0f;
        bfrag[1] = (_Float16)qx;
        bfrag[2] = (_Float16)qy;
        bfrag[3] = (_Float16)qz;
    }

    // ---- staging: 1 row per thread per chunk (scalar loads) ----
    float pa[3];
    auto loadpts = [&](int c) {
        const float* base = Pb + ((size_t)c * CH_CHUNK + tid) * 3;
        pa[0] = base[0];
        pa[1] = base[1];
        pa[2] = base[2];
    };
    auto writept = [&](int buf) {
        const float ax = -2.0f * pa[0], ay = -2.0f * pa[1], az = -2.0f * pa[2];
        const float pn = pa[0] * pa[0] + pa[1] * pa[1] + pa[2] * pa[2];
        const _Float16 axh = (_Float16)ax, ayh = (_Float16)ay, azh = (_Float16)az;
        const _Float16 pnh = (_Float16)pn;
        const half4 k0 = {pnh, axh, ayh, azh};                       // k 0..3
        const half4 k1 = {(_Float16)(pn - (float)pnh),
                          (_Float16)(ax - (float)axh),
                          (_Float16)(ay - (float)ayh),
                          (_Float16)(az - (float)azh)};              // k 4..7
        sp[buf][(tid >> 5) * 64 + (tid & 31)]      = k0;
        sp[buf][(tid >> 5) * 64 + 32 + (tid & 31)] = k1;
    };

    // prologue: stage chunk 0
    loadpts(0);
    writept(0);
    __syncthreads();

    const floatx16 zero = {0.f,0.f,0.f,0.f,0.f,0.f,0.f,0.f,
                           0.f,0.f,0.f,0.f,0.f,0.f,0.f,0.f};

    // min3-shaped reduction of one MFMA result into m
    auto tree = [&](const floatx16& d) {
        const float u0 = fminf(fminf(d[0],  d[1]),  d[2]);
        const float u1 = fminf(fminf(d[3],  d[4]),  d[5]);
        const float u2 = fminf(fminf(d[6],  d[7]),  d[8]);
        const float u3 = fminf(fminf(d[9],  d[10]), d[11]);
        const float u4 = fminf(fminf(d[12], d[13]), d[14]);
        const float v  = fminf(fminf(u0, u1), u2);
        const float w  = fminf(fminf(u3, u4), d[15]);
        m = fminf(fminf(m, v), w);
    };

    #pragma unroll 1
    for (int c = 0; c < CH_NCHUNK; ++c) {
        const int cur = c & 1;
        const bool more = (c + 1 < CH_NCHUNK);
        if (more) loadpts(c + 1);   // issue early; consumed after compute

        const half4* buf = sp[cur];

        // 4-deep A prefetch + 2-slot d pipeline (max 3 live floatx16)
        half4 A0 = buf[0 * 64 + lane];
        half4 A1 = buf[1 * 64 + lane];
        half4 A2 = buf[2 * 64 + lane];
        half4 A3 = buf[3 * 64 + lane];
        floatx16 d0 = __builtin_amdgcn_mfma_f32_32x32x8f16(A0, bfrag, zero, 0, 0, 0);
        floatx16 d1 = __builtin_amdgcn_mfma_f32_32x32x8f16(A1, bfrag, zero, 0, 0, 0);

        #pragma unroll 1
        for (int t = 0; t <= CH_CT - 8; t += 4) {   // t = 0..24
            floatx16 d2 = __builtin_amdgcn_mfma_f32_32x32x8f16(A2, bfrag, zero, 0, 0, 0);
            A0 = buf[(t + 4) * 64 + lane];
            tree(d0);
            floatx16 d3 = __builtin_amdgcn_mfma_f32_32x32x8f16(A3, bfrag, zero, 0, 0, 0);
            A1 = buf[(t + 5) * 64 + lane];
            tree(d1);
            d0 = __builtin_amdgcn_mfma_f32_32x32x8f16(A0, bfrag, zero, 0, 0, 0);
            A2 = buf[(t + 6) * 64 + lane];
            tree(d2);
            d1 = __builtin_amdgcn_mfma_f32_32x32x8f16(A1, bfrag, zero, 0, 0, 0);
            A3 = buf[(t + 7) * 64 + lane];
            tree(d3);
        }
        // epilogue: d0=tile CT-4, d1=tile CT-3; A2,A3 hold tiles CT-2, CT-1
        {
            floatx16 e2 = __builtin_amdgcn_mfma_f32_32x32x8f16(A2, bfrag, zero, 0, 0, 0);
            tree(d0);
            floatx16 e3 = __builtin_amdgcn_mfma_f32_32x32x8f16(A3, bfrag, zero, 0, 0, 0);
            tree(d1);
            tree(e2);
            tree(e3);
        }

        if (more) writept(cur ^ 1);   // LDS writes late (load latency hidden)
        __syncthreads();
    }

    // ---- epilogue: add ||q||^2, clamp >=0, fold row-halves, plain store ----
    float v = fmaxf(m + qn, 0.0f);
    v = fminf(v, __shfl_xor(v, 32));
    if (lane < 32) out[col0] = v;
}

extern "C" void kernel_launch(void* const* d_in, const int* in_sizes, int n_in,
                              void* d_out, int out_size, void* d_ws, size_t ws_size,
                              hipStream_t stream) {
    const float* src = (const float*)d_in[0];
    const float* trg = (const float*)d_in[1];
    float* out = (float*)d_out;

    chamfer_one<<<dim3(CH_NBLK), dim3(CH_BLOCK), 0, stream>>>(src, trg, out);
}